// Round 4
// baseline (287.303 us; speedup 1.0000x reference)
//
#include <hip/hip_runtime.h>
#include <math.h>

#define VOCAB 50000
#define EMB   100
#define KP    128      // K padded for MFMA
#define BATCH 2048
#define CTX   10

#define NVT   391      // 128-wide vocab tiles (391*128 = 50048)
#define BC    4        // batch chunks (grid.x); block covers 512 b in 4 subtiles of 128
#define PROWS (2 * NVT)  // partial rows: (vy, v-half)

typedef __attribute__((ext_vector_type(8))) short short8;
typedef __attribute__((ext_vector_type(4))) float f32x4;

__device__ __forceinline__ unsigned short f2bf(float x) {
    union { float f; unsigned u; } v; v.f = x;
    unsigned r = (v.u + 0x7FFFu + ((v.u >> 16) & 1u)) >> 16;  // RNE
    return (unsigned short)r;
}

// ---------------- h = mean of context embeddings; fp32 (pos term) + bf16 padded; zero out ----------------
__global__ void k_h(const int* __restrict__ x, const float* __restrict__ emb_v,
                    float* __restrict__ hf, unsigned short* __restrict__ hb,
                    float* __restrict__ out) {
    const int b = blockIdx.x;
    const int e = threadIdx.x;  // 0..127
    if (b == 0 && e == 0) out[0] = 0.0f;
    float s = 0.0f;
    if (e < EMB) {
#pragma unroll
        for (int c = 0; c < CTX; ++c) {
            const int idx = x[b * CTX + c];
            s += emb_v[idx * EMB + e];
        }
        s *= (1.0f / CTX);
        hf[b * EMB + e] = s;
    }
    hb[b * KP + e] = (e < EMB) ? f2bf(s) : (unsigned short)0;
}

// ---------------- fused bf16-MFMA GEMM + sigmoid row-sum ----------------
// A = u (m axis = v), B = h (n axis = b). D: col(lane&15)=b, row(q*4+reg)=v.
// u-tile converted fp32->bf16 into LDS once per block; main loop has NO barriers,
// NO atomics: wave-disjoint partial[2*vy + vhalf][b] slots.
__global__ __launch_bounds__(256, 3)
void k_neg(const unsigned short* __restrict__ hb, const float* __restrict__ u,
           float* __restrict__ partial) {
    __shared__ unsigned short us[128][136];   // +8 pad: b128 frag reads spread banks

    const int t   = threadIdx.x;
    const int w   = t >> 6;          // wave 0..3
    const int L   = t & 63;
    const int c16 = L & 15;
    const int q   = L >> 4;
    const int wm  = (w & 1) * 64;    // wave v-offset within 128-tile
    const int wn  = (w >> 1) * 64;   // wave b-offset within 128-subtile
    const int vy  = blockIdx.y;
    const int v0  = vy * 128;
    const int bbase = blockIdx.x * (BATCH / BC);   // 512 per chunk

    // ---- stage u tile: 128 rows x 128 cols bf16 (cols>=100 and rows>=VOCAB zeroed) ----
#pragma unroll
    for (int i = 0; i < 2; ++i) {
        const int sg  = t + 256 * i;        // 512 segments of 32 cols
        const int row = sg >> 2;
        const int s4  = sg & 3;
        const int cs  = s4 * 32;
        const int gr  = v0 + row;
        short8 o[4];
        if (gr < VOCAB && s4 < 3) {          // cols 0..95, all valid
            const float4* p = (const float4*)&u[gr * EMB + cs];
#pragma unroll
            for (int j = 0; j < 4; ++j) {
                const float4 a = p[2 * j], b2 = p[2 * j + 1];
                o[j][0] = (short)f2bf(a.x);  o[j][1] = (short)f2bf(a.y);
                o[j][2] = (short)f2bf(a.z);  o[j][3] = (short)f2bf(a.w);
                o[j][4] = (short)f2bf(b2.x); o[j][5] = (short)f2bf(b2.y);
                o[j][6] = (short)f2bf(b2.z); o[j][7] = (short)f2bf(b2.w);
            }
        } else {
#pragma unroll
            for (int j = 0; j < 4; ++j) o[j] = (short8)(short)0;
            if (gr < VOCAB) {                // s4==3: cols 96..99 valid
                const float4 a = *(const float4*)&u[gr * EMB + 96];
                o[0][0] = (short)f2bf(a.x); o[0][1] = (short)f2bf(a.y);
                o[0][2] = (short)f2bf(a.z); o[0][3] = (short)f2bf(a.w);
            }
        }
#pragma unroll
        for (int j = 0; j < 4; ++j)
            *(short8*)&us[row][cs + 8 * j] = o[j];
    }
    __syncthreads();   // the only barrier

#pragma unroll 1
    for (int bt = 0; bt < (BATCH / BC) / 128; ++bt) {   // 4 subtiles of 128 b
        const int b0 = bbase + bt * 128;

        f32x4 acc[4][4];
#pragma unroll
        for (int mi = 0; mi < 4; ++mi)
#pragma unroll
            for (int ni = 0; ni < 4; ++ni) acc[mi][ni] = (f32x4)(0.0f);

#pragma unroll
        for (int kc = 0; kc < 4; ++kc) {
            short8 af[4], bf[4];
#pragma unroll
            for (int mi = 0; mi < 4; ++mi)
                af[mi] = *(const short8*)&us[wm + mi * 16 + c16][kc * 32 + q * 8];
#pragma unroll
            for (int ni = 0; ni < 4; ++ni)
                bf[ni] = *(const short8*)&hb[(b0 + wn + ni * 16 + c16) * KP + kc * 32 + q * 8];
#pragma unroll
            for (int mi = 0; mi < 4; ++mi)
#pragma unroll
                for (int ni = 0; ni < 4; ++ni)
                    acc[mi][ni] = __builtin_amdgcn_mfma_f32_16x16x32_bf16(
                        af[mi], bf[ni], acc[mi][ni], 0, 0, 0);
        }

        // ---- epilogue: sum_v sigmoid(-score) per b column; pairwise to halve rcp ----
#pragma unroll
        for (int ni = 0; ni < 4; ++ni) {
            float p = 0.0f;
#pragma unroll
            for (int mi = 0; mi < 4; ++mi) {
                const int vb = v0 + wm + mi * 16 + q * 4;   // v of reg 0 (uniform over c16)
#pragma unroll
                for (int pr = 0; pr < 2; ++pr) {
                    if (vb + pr * 2 < VOCAB) {   // pairs start even; VOCAB even
                        const float ea = __expf(acc[mi][ni][2 * pr + 0]);
                        const float eb = __expf(acc[mi][ni][2 * pr + 1]);
                        const float num = 2.0f + ea + eb;
                        const float den = (1.0f + ea) * (1.0f + eb);
                        p = fmaf(num, __builtin_amdgcn_rcpf(den), p);
                    }
                }
            }
            p += __shfl_down(p, 32);   // fold q
            p += __shfl_down(p, 16);
            if (L < 16)
                partial[(2 * vy + (w & 1)) * BATCH + b0 + wn + ni * 16 + L] = p;
        }
    }
}

// ---------------- final: reduce partial rows + pos term + mean ----------------
__global__ void k_final(const int* __restrict__ y, const float* __restrict__ hf,
                        const float* __restrict__ u, const float* __restrict__ partial,
                        float* __restrict__ out) {
    const int b = blockIdx.x * 256 + threadIdx.x;   // 8 blocks x 256
    float ns = 0.0f;
#pragma unroll 4
    for (int r = 0; r < PROWS; ++r) ns += partial[r * BATCH + b];   // coalesced

    const int yi = y[b];
    const float4* hp = (const float4*)&hf[b * EMB];
    const float4* up = (const float4*)&u[yi * EMB];
    float dot = 0.0f;
#pragma unroll
    for (int qq = 0; qq < EMB / 4; ++qq) {
        const float4 a = hp[qq];
        const float4 c = up[qq];
        dot += a.x * c.x + a.y * c.y + a.z * c.z + a.w * c.w;
    }
    const float pos = fmaxf(-dot, 0.0f) + log1pf(__expf(-fabsf(dot)));  // softplus(-dot)
    float val = pos + logf(ns);
#pragma unroll
    for (int off = 32; off; off >>= 1) val += __shfl_down(val, off, 64);
    if ((threadIdx.x & 63) == 0) atomicAdd(out, val * (1.0f / BATCH));
}

extern "C" void kernel_launch(void* const* d_in, const int* in_sizes, int n_in,
                              void* d_out, int out_size, void* d_ws, size_t ws_size,
                              hipStream_t stream) {
    const int*   x     = (const int*)d_in[0];
    const int*   y     = (const int*)d_in[1];
    const float* emb_v = (const float*)d_in[2];
    const float* emb_u = (const float*)d_in[3];
    float* out = (float*)d_out;

    // workspace carve (~7.8 MB), 16B-aligned sections
    float*          hf      = (float*)d_ws;                        // 2048*100 fp32
    float*          partial = hf + BATCH * EMB;                    // 782*2048 fp32
    unsigned short* hb      = (unsigned short*)(partial + PROWS * BATCH);  // 2048*128 bf16

    k_h    <<<dim3(BATCH), dim3(128), 0, stream>>>(x, emb_v, hf, hb, out);
    k_neg  <<<dim3(BC, NVT), dim3(256), 0, stream>>>(hb, emb_u, partial);
    k_final<<<dim3(BATCH / 256), dim3(256), 0, stream>>>(y, hf, emb_u, partial, out);
}

// Round 5
// 180.487 us; speedup vs baseline: 1.5918x; 1.5918x over previous
//
#include <hip/hip_runtime.h>
#include <math.h>

#define VOCAB 50000
#define EMB   100
#define KP    128      // K padded for MFMA
#define BATCH 2048
#define CTX   10

#define NVT   391        // 128-wide vocab tiles (391*128 = 50048)
#define BC    2          // batch chunks; block covers 1024 b in 8 subtiles of 128
#define PROWS (2 * NVT)  // partial rows: (vy, v-half) = 782

typedef __attribute__((ext_vector_type(8))) short short8;
typedef __attribute__((ext_vector_type(4))) float f32x4;

__device__ __forceinline__ unsigned short f2bf(float x) {
    union { float f; unsigned u; } v; v.f = x;
    unsigned r = (v.u + 0x7FFFu + ((v.u >> 16) & 1u)) >> 16;  // RNE
    return (unsigned short)r;
}

// ---------------- h = mean of context embeddings (256 chunky blocks) ----------------
// Also zeroes neg_sum and out (k_red/k_final accumulate later in stream order).
__global__ void k_h(const int* __restrict__ x, const float* __restrict__ emb_v,
                    float* __restrict__ hf, unsigned short* __restrict__ hb,
                    float* __restrict__ neg_sum, float* __restrict__ out) {
    const int t = threadIdx.x;
    const int g = t >> 7;        // half-block 0/1
    const int e = t & 127;
    if (blockIdx.x == 0 && t == 0) out[0] = 0.0f;
    if (t < 8) neg_sum[blockIdx.x * 8 + t] = 0.0f;
#pragma unroll
    for (int i = 0; i < 4; ++i) {
        const int b = blockIdx.x * 8 + g * 4 + i;
        float s = 0.0f;
        if (e < EMB) {
#pragma unroll
            for (int c = 0; c < CTX; ++c) {
                const int idx = x[b * CTX + c];
                s += emb_v[idx * EMB + e];
            }
            s *= (1.0f / CTX);
            hf[b * EMB + e] = s;
        }
        hb[b * KP + e] = (e < EMB) ? f2bf(s) : (unsigned short)0;
    }
}

// ---------------- fused bf16-MFMA GEMM + sigmoid row-sum ----------------
// A = u (m=v), B = h (n=b). D: col(lane&15)=b, row(q*4+reg)=v.
// u-tile fp32->bf16 into LDS once; a-frags LDS->64 VGPRs ONCE, reused 8 subtiles.
// b-frags: 16 global b128 loads/subtile from L2-hot hb. No atomics, no loop barriers.
__global__ __launch_bounds__(256, 2)
void k_neg(const unsigned short* __restrict__ hb, const float* __restrict__ u,
           float* __restrict__ partial) {
    __shared__ unsigned short us[128][136];   // +8 pad for bank spread

    const int t   = threadIdx.x;
    const int w   = t >> 6;          // wave 0..3
    const int L   = t & 63;
    const int c16 = L & 15;
    const int q   = L >> 4;
    const int wm  = (w & 1) * 64;    // wave v-offset within 128-tile
    const int wn  = (w >> 1) * 64;   // wave b-offset within 128-subtile
    const int vy  = blockIdx.y;
    const int v0  = vy * 128;

    // ---- stage u tile: 128 v-rows x 128 k (fp32 -> bf16; pad rows/cols zeroed) ----
#pragma unroll
    for (int i = 0; i < 2; ++i) {
        const int sg  = t + 256 * i;        // 512 segments of 32 cols
        const int row = sg >> 2;
        const int s4  = sg & 3;
        const int cs  = s4 * 32;
        const int gr  = v0 + row;
        short8 o[4];
        if (gr < VOCAB && s4 < 3) {          // cols 0..95 all valid
            const float4* p = (const float4*)&u[gr * EMB + cs];
#pragma unroll
            for (int j = 0; j < 4; ++j) {
                const float4 a = p[2 * j], b2 = p[2 * j + 1];
                o[j][0] = (short)f2bf(a.x);  o[j][1] = (short)f2bf(a.y);
                o[j][2] = (short)f2bf(a.z);  o[j][3] = (short)f2bf(a.w);
                o[j][4] = (short)f2bf(b2.x); o[j][5] = (short)f2bf(b2.y);
                o[j][6] = (short)f2bf(b2.z); o[j][7] = (short)f2bf(b2.w);
            }
        } else {
#pragma unroll
            for (int j = 0; j < 4; ++j) o[j] = (short8)(short)0;
            if (gr < VOCAB) {                // s4==3: cols 96..99 valid
                const float4 a = *(const float4*)&u[gr * EMB + 96];
                o[0][0] = (short)f2bf(a.x); o[0][1] = (short)f2bf(a.y);
                o[0][2] = (short)f2bf(a.z); o[0][3] = (short)f2bf(a.w);
            }
        }
#pragma unroll
        for (int j = 0; j < 4; ++j)
            *(short8*)&us[row][cs + 8 * j] = o[j];
    }
    __syncthreads();   // the only barrier

    // ---- a-frags: LDS -> registers once (64 VGPRs), reused for all 8 subtiles ----
    short8 af[4][4];   // [kc][mi]
#pragma unroll
    for (int kc = 0; kc < 4; ++kc)
#pragma unroll
        for (int mi = 0; mi < 4; ++mi)
            af[kc][mi] = *(const short8*)&us[wm + mi * 16 + c16][kc * 32 + q * 8];

    const int prow = (2 * vy + (w & 1)) * BATCH;

#pragma unroll 1
    for (int bt = 0; bt < (BATCH / BC) / 128; ++bt) {   // 8 subtiles of 128 b
        const int b0 = blockIdx.x * (BATCH / BC) + bt * 128;

        // 16 independent global b128 loads; fine-grained vmcnt lets kc0 MFMAs
        // start while kc1..3 loads are still in flight.
        short8 bf[4][4];   // [kc][ni]
#pragma unroll
        for (int kc = 0; kc < 4; ++kc)
#pragma unroll
            for (int ni = 0; ni < 4; ++ni)
                bf[kc][ni] = *(const short8*)&hb[(b0 + wn + ni * 16 + c16) * KP + kc * 32 + q * 8];

        f32x4 acc[4][4];
#pragma unroll
        for (int mi = 0; mi < 4; ++mi)
#pragma unroll
            for (int ni = 0; ni < 4; ++ni) acc[mi][ni] = (f32x4)(0.0f);

#pragma unroll
        for (int kc = 0; kc < 4; ++kc)
#pragma unroll
            for (int mi = 0; mi < 4; ++mi)
#pragma unroll
                for (int ni = 0; ni < 4; ++ni)
                    acc[mi][ni] = __builtin_amdgcn_mfma_f32_16x16x32_bf16(
                        af[kc][mi], bf[kc][ni], acc[mi][ni], 0, 0, 0);

        // ---- epilogue: sum_v sigmoid(-score); pairwise halves the rcp count ----
#pragma unroll
        for (int ni = 0; ni < 4; ++ni) {
            float p = 0.0f;
#pragma unroll
            for (int mi = 0; mi < 4; ++mi) {
                const int vb = v0 + wm + mi * 16 + q * 4;   // multiple of 4; pairs never straddle VOCAB
#pragma unroll
                for (int pr = 0; pr < 2; ++pr) {
                    if (vb + pr * 2 < VOCAB) {
                        const float ea = __expf(acc[mi][ni][2 * pr + 0]);
                        const float eb = __expf(acc[mi][ni][2 * pr + 1]);
                        const float num = 2.0f + ea + eb;
                        const float den = (1.0f + ea) * (1.0f + eb);
                        p = fmaf(num, __builtin_amdgcn_rcpf(den), p);
                    }
                }
            }
            p += __shfl_down(p, 32);   // fold q
            p += __shfl_down(p, 16);
            if (L < 16)
                partial[prow + b0 + wn + ni * 16 + L] = p;
        }
    }
}

// ---------------- parallel reduction of partial rows -> neg_sum ----------------
// grid (32 b-chunks x 8 row-chunks), block 256 = 64 b-lanes x 4 row-waves.
__global__ void k_red(const float* __restrict__ partial, float* __restrict__ neg_sum) {
    const int t    = threadIdx.x;
    const int lane = t & 63;
    const int w    = t >> 6;
    const int b    = blockIdx.x * 64 + lane;
    const int r0   = blockIdx.y * 98;
    const int r1   = (r0 + 98 < PROWS) ? r0 + 98 : PROWS;
    float s = 0.0f;
#pragma unroll 4
    for (int r = r0 + w; r < r1; r += 4)
        s += partial[r * BATCH + b];     // coalesced across 64 lanes
    __shared__ float red[4][64];
    red[w][lane] = s;
    __syncthreads();
    if (w == 0)
        atomicAdd(&neg_sum[b], red[0][lane] + red[1][lane] + red[2][lane] + red[3][lane]);
}

// ---------------- final: pos term + log(neg_sum) + mean ----------------
__global__ void k_final(const int* __restrict__ y, const float* __restrict__ hf,
                        const float* __restrict__ u, const float* __restrict__ neg_sum,
                        float* __restrict__ out) {
    const int b = blockIdx.x * 256 + threadIdx.x;
    const int yi = y[b];
    const float4* hp = (const float4*)&hf[b * EMB];
    const float4* up = (const float4*)&u[yi * EMB];
    float dot = 0.0f;
#pragma unroll
    for (int qq = 0; qq < EMB / 4; ++qq) {
        const float4 a = hp[qq];
        const float4 c = up[qq];
        dot += a.x * c.x + a.y * c.y + a.z * c.z + a.w * c.w;
    }
    const float pos = fmaxf(-dot, 0.0f) + log1pf(__expf(-fabsf(dot)));  // softplus(-dot)
    float val = pos + logf(neg_sum[b]);
#pragma unroll
    for (int off = 32; off; off >>= 1) val += __shfl_down(val, off, 64);
    if ((threadIdx.x & 63) == 0) atomicAdd(out, val * (1.0f / BATCH));
}

extern "C" void kernel_launch(void* const* d_in, const int* in_sizes, int n_in,
                              void* d_out, int out_size, void* d_ws, size_t ws_size,
                              hipStream_t stream) {
    const int*   x     = (const int*)d_in[0];
    const int*   y     = (const int*)d_in[1];
    const float* emb_v = (const float*)d_in[2];
    const float* emb_u = (const float*)d_in[3];
    float* out = (float*)d_out;

    // workspace carve (~7.8 MB), all 16B-aligned
    float*          hf      = (float*)d_ws;                          // 2048*100 fp32
    float*          partial = hf + BATCH * EMB;                      // 782*2048 fp32
    float*          neg_sum = partial + PROWS * BATCH;               // 2048 fp32
    unsigned short* hb      = (unsigned short*)(neg_sum + BATCH);    // 2048*128 bf16

    k_h    <<<dim3(BATCH / 8), dim3(256), 0, stream>>>(x, emb_v, hf, hb, neg_sum, out);
    k_neg  <<<dim3(BC, NVT), dim3(256), 0, stream>>>(hb, emb_u, partial);
    k_red  <<<dim3(BATCH / 64, 8), dim3(256), 0, stream>>>(partial, neg_sum);
    k_final<<<dim3(BATCH / 256), dim3(256), 0, stream>>>(y, hf, emb_u, neg_sum, out);
}

// Round 6
// 174.940 us; speedup vs baseline: 1.6423x; 1.0317x over previous
//
#include <hip/hip_runtime.h>
#include <math.h>

#define VOCAB 50000
#define EMB   100
#define KP    128        // hb row stride (shorts)
#define KP2   136        // ub/us row stride (shorts): 272 B, 16B-aligned, bank-friendly
#define BATCH 2048
#define CTX   10

#define NVT   391        // 128-wide vocab tiles (391*128 = 50048)
#define BC    4          // batch chunks; block covers 512 b in 4 subtiles of 128
#define PROWS (2 * NVT)  // partial rows: (vy, v-half) = 782

typedef __attribute__((ext_vector_type(8))) short short8;
typedef __attribute__((ext_vector_type(4))) float f32x4;

__device__ __forceinline__ unsigned short f2bf(float x) {
    union { float f; unsigned u; } v; v.f = x;
    unsigned r = (v.u + 0x7FFFu + ((v.u >> 16) & 1u)) >> 16;  // RNE
    return (unsigned short)r;
}

// ---------------- dense pre-convert: emb_u fp32 [50000][100] -> bf16 ub[50000][136] ----------------
// Rows 0..49999 written (cols 100..135 zero). Rows 50000..50047 of the last tile are
// never accumulated (epilogue guards v < VOCAB), so they may stay poisoned.
__global__ void k_cvt(const float* __restrict__ u, unsigned short* __restrict__ ub) {
    const int c = blockIdx.x * 256 + threadIdx.x;   // 17 x 16B chunks per row
    if (c >= VOCAB * 17) return;
    const int row = c / 17;
    const int seg = c % 17;
    short8 o = (short8)(short)0;
    if (seg < 12) {          // cols seg*8 .. +8, all < 96+? (11*8+8=96 <= 100) valid
        const float4* p = (const float4*)&u[row * EMB + seg * 8];
        const float4 a = p[0], b = p[1];
        o[0] = (short)f2bf(a.x); o[1] = (short)f2bf(a.y);
        o[2] = (short)f2bf(a.z); o[3] = (short)f2bf(a.w);
        o[4] = (short)f2bf(b.x); o[5] = (short)f2bf(b.y);
        o[6] = (short)f2bf(b.z); o[7] = (short)f2bf(b.w);
    } else if (seg == 12) {  // cols 96..99 valid, 100..103 zero
        const float4 a = *(const float4*)&u[row * EMB + 96];
        o[0] = (short)f2bf(a.x); o[1] = (short)f2bf(a.y);
        o[2] = (short)f2bf(a.z); o[3] = (short)f2bf(a.w);
    }                        // seg 13..16: zeros
    *(short8*)&ub[row * KP2 + seg * 8] = o;
}

// ---------------- h = mean of context embeddings; fp32 (pos term) + bf16 padded ----------------
__global__ void k_h(const int* __restrict__ x, const float* __restrict__ emb_v,
                    float* __restrict__ hf, unsigned short* __restrict__ hb,
                    float* __restrict__ out) {
    const int b = blockIdx.x;
    const int e = threadIdx.x;  // 0..127
    if (b == 0 && e == 0) out[0] = 0.0f;
    float s = 0.0f;
    if (e < EMB) {
#pragma unroll
        for (int c = 0; c < CTX; ++c) {
            const int idx = x[b * CTX + c];
            s += emb_v[idx * EMB + e];
        }
        s *= (1.0f / CTX);
        hf[b * EMB + e] = s;
    }
    hb[b * KP + e] = (e < EMB) ? f2bf(s) : (unsigned short)0;
}

// ---------------- fused bf16-MFMA GEMM + sigmoid row-sum ----------------
// A = u (m=v), B = h (n=b). D: col(lane&15)=b, row(q*4+reg)=v.
// u-tile staged as a FLAT CONTIGUOUS memcpy (lane-consecutive 16B -> dense HBM bursts,
// no convert VALU, 2-way-only LDS banks). af LDS->regs once; bf from L2-hot hb.
// No loop barriers, no atomics (wave-disjoint partial rows).
__global__ __launch_bounds__(256, 2)
void k_neg(const unsigned short* __restrict__ hb, const unsigned short* __restrict__ ub,
           float* __restrict__ partial) {
    __shared__ unsigned short us[128 * KP2];   // 34816 B, flat copy of the ub tile

    const int t   = threadIdx.x;
    const int w   = t >> 6;          // wave 0..3
    const int L   = t & 63;
    const int c16 = L & 15;
    const int q   = L >> 4;
    const int wm  = (w & 1) * 64;    // wave v-offset within 128-tile
    const int wn  = (w >> 1) * 64;   // wave b-offset within 128-subtile
    const int vy  = blockIdx.y;
    const int v0  = vy * 128;

    // ---- stage u tile: 128*272 B contiguous, 2176 chunks of 16 B ----
    const unsigned short* src = ub + (size_t)v0 * KP2;
#pragma unroll
    for (int i = 0; i < 8; ++i)
        *(short8*)&us[(i * 256 + t) * 8] = *(const short8*)&src[(i * 256 + t) * 8];
    if (t < 128)
        *(short8*)&us[(2048 + t) * 8] = *(const short8*)&src[(2048 + t) * 8];
    __syncthreads();   // the only barrier

    // ---- a-frags: LDS -> 64 VGPRs once, reused for all subtiles ----
    short8 af[4][4];   // [kc][mi]
#pragma unroll
    for (int kc = 0; kc < 4; ++kc)
#pragma unroll
        for (int mi = 0; mi < 4; ++mi)
            af[kc][mi] = *(const short8*)&us[(wm + mi * 16 + c16) * KP2 + kc * 32 + q * 8];

    const int prow = (2 * vy + (w & 1)) * BATCH;

#pragma unroll 1
    for (int bt = 0; bt < (BATCH / BC) / 128; ++bt) {   // 4 subtiles of 128 b
        const int b0 = blockIdx.x * (BATCH / BC) + bt * 128;

        short8 bf[4][4];   // [kc][ni] -- 16 independent b128 loads from L2-hot hb
#pragma unroll
        for (int kc = 0; kc < 4; ++kc)
#pragma unroll
            for (int ni = 0; ni < 4; ++ni)
                bf[kc][ni] = *(const short8*)&hb[(b0 + wn + ni * 16 + c16) * KP + kc * 32 + q * 8];

        f32x4 acc[4][4];
#pragma unroll
        for (int mi = 0; mi < 4; ++mi)
#pragma unroll
            for (int ni = 0; ni < 4; ++ni) acc[mi][ni] = (f32x4)(0.0f);

#pragma unroll
        for (int kc = 0; kc < 4; ++kc)
#pragma unroll
            for (int mi = 0; mi < 4; ++mi)
#pragma unroll
                for (int ni = 0; ni < 4; ++ni)
                    acc[mi][ni] = __builtin_amdgcn_mfma_f32_16x16x32_bf16(
                        af[kc][mi], bf[kc][ni], acc[mi][ni], 0, 0, 0);

        // ---- epilogue: sum_v sigmoid(-score); pairwise halves the rcp count ----
#pragma unroll
        for (int ni = 0; ni < 4; ++ni) {
            float p = 0.0f;
#pragma unroll
            for (int mi = 0; mi < 4; ++mi) {
                const int vb = v0 + wm + mi * 16 + q * 4;   // multiple of 4; pairs never straddle
#pragma unroll
                for (int pr = 0; pr < 2; ++pr) {
                    if (vb + pr * 2 < VOCAB) {
                        const float ea = __expf(acc[mi][ni][2 * pr + 0]);
                        const float eb = __expf(acc[mi][ni][2 * pr + 1]);
                        const float num = 2.0f + ea + eb;
                        const float den = (1.0f + ea) * (1.0f + eb);
                        p = fmaf(num, __builtin_amdgcn_rcpf(den), p);
                    }
                }
            }
            p += __shfl_down(p, 32);   // fold q
            p += __shfl_down(p, 16);
            if (L < 16)
                partial[prow + b0 + wn + ni * 16 + L] = p;
        }
    }
}

// ---------------- reduce partial rows + pos term + mean, in one kernel ----------------
// 32 blocks x 512 threads: 64 b-lanes x 8 row-waves, coalesced across b.
__global__ void k_redfinal(const int* __restrict__ y, const float* __restrict__ hf,
                           const float* __restrict__ u, const float* __restrict__ partial,
                           float* __restrict__ out) {
    const int t    = threadIdx.x;
    const int lane = t & 63;
    const int w    = t >> 6;
    const int b    = blockIdx.x * 64 + lane;
    float s = 0.0f;
#pragma unroll 4
    for (int r = w; r < PROWS; r += 8)
        s += partial[r * BATCH + b];     // coalesced across 64 lanes
    __shared__ float red[8][64];
    red[w][lane] = s;
    __syncthreads();
    if (w == 0) {
        float ns = 0.0f;
#pragma unroll
        for (int i = 0; i < 8; ++i) ns += red[i][lane];

        const int yi = y[b];
        const float4* hp = (const float4*)&hf[b * EMB];
        const float4* up = (const float4*)&u[yi * EMB];
        float dot = 0.0f;
#pragma unroll
        for (int qq = 0; qq < EMB / 4; ++qq) {
            const float4 a = hp[qq];
            const float4 c = up[qq];
            dot += a.x * c.x + a.y * c.y + a.z * c.z + a.w * c.w;
        }
        const float pos = fmaxf(-dot, 0.0f) + log1pf(__expf(-fabsf(dot)));  // softplus(-dot)
        float val = pos + logf(ns);
#pragma unroll
        for (int off = 32; off; off >>= 1) val += __shfl_down(val, off, 64);
        if (lane == 0) atomicAdd(out, val * (1.0f / BATCH));
    }
}

extern "C" void kernel_launch(void* const* d_in, const int* in_sizes, int n_in,
                              void* d_out, int out_size, void* d_ws, size_t ws_size,
                              hipStream_t stream) {
    const int*   x     = (const int*)d_in[0];
    const int*   y     = (const int*)d_in[1];
    const float* emb_v = (const float*)d_in[2];
    const float* emb_u = (const float*)d_in[3];
    float* out = (float*)d_out;

    // workspace carve (~21.4 MB), all sections 16B-aligned
    float*          hf      = (float*)d_ws;                          // 2048*100 fp32
    float*          partial = hf + BATCH * EMB;                      // 782*2048 fp32
    unsigned short* hb      = (unsigned short*)(partial + PROWS * BATCH);  // 2048*128 bf16
    unsigned short* ub      = hb + BATCH * KP;                       // 50048*136 bf16

    k_cvt     <<<dim3((VOCAB * 17 + 255) / 256), dim3(256), 0, stream>>>(emb_u, ub);
    k_h       <<<dim3(BATCH), dim3(128), 0, stream>>>(x, emb_v, hf, hb, out);
    k_neg     <<<dim3(BC, NVT), dim3(256), 0, stream>>>(hb, ub, partial);
    k_redfinal<<<dim3(BATCH / 64), dim3(512), 0, stream>>>(y, hf, emb_u, partial, out);
}